// Round 2
// baseline (29214.349 us; speedup 1.0000x reference)
//
#include <hip/hip_runtime.h>
#include <hip/hip_bf16.h>

#define T_SZ   256
#define EMB    128
#define NH     256
#define NCLASS 32000
#define BSZ    2048
#define BH     (BSZ * NH)   // elems per parity buffer (524288)

typedef __bf16 bf16;
typedef __bf16 bf16x8 __attribute__((ext_vector_type(8)));
typedef float  f32x4  __attribute__((ext_vector_type(4)));
typedef float  f32x16 __attribute__((ext_vector_type(16)));

#define A1S  392   // A1 row stride elems: [x(128)|h1(256)] + 8 pad
#define A2S  264   // A2 row stride elems: h2(256) + 8 pad
#define GSTR 33    // wave-private gate scratch row stride (fp32)

__device__ __forceinline__ float sigf(float x)     { return 1.0f / (1.0f + __expf(-x)); }
__device__ __forceinline__ float tanhfast(float x) { return 2.0f / (1.0f + __expf(-2.0f * x)) - 1.0f; }

// chunk-XOR swizzle: 16B-chunk c of row -> physical chunk. Kills the 4-way
// bank conflict among rows {r, r+8, r+16, r+24} (row strides are ≡16 mod 32 banks).
__device__ __forceinline__ int chsw(int row, int c) { return c ^ (((row >> 3) & 3) << 1); }

struct GatePtrs {
    const float* U1[4];
    const float* V1[4];
    const float* U2[4];
    const float* V2[4];
};

// gc layout (per layer): gc = nhblock*32 + gate*8 + nhoff ; nh = nhblock*8 + nhoff
__global__ void prep_w1(GatePtrs gp, bf16* __restrict__ Wt1) {
    int gc = blockIdx.x;              // 0..1023
    int k  = threadIdx.x;             // 0..383
    int g  = (gc >> 3) & 3;
    int nh = ((gc >> 5) << 3) | (gc & 7);
    float v = (k < EMB) ? gp.U1[g][k * NH + nh] : gp.V1[g][(k - EMB) * NH + nh];
    Wt1[gc * 384 + k] = (bf16)v;
}

__global__ void prep_w2(GatePtrs gp, bf16* __restrict__ Wt2) {
    int gc = blockIdx.x;
    int k  = threadIdx.x;             // 0..511
    int g  = (gc >> 3) & 3;
    int nh = ((gc >> 5) << 3) | (gc & 7);
    float v = (k < NH) ? gp.U2[g][k * NH + nh] : gp.V2[g][(k - NH) * NH + nh];
    Wt2[gc * 512 + k] = (bf16)v;
}

__global__ void prep_wo(const float* __restrict__ Wo, bf16* __restrict__ WoT) {
    __shared__ float tile[32][33];
    int n0 = blockIdx.x * 32;
    int k0 = blockIdx.y * 32;
    int tx = threadIdx.x & 31;
    int ty = threadIdx.x >> 5;
#pragma unroll
    for (int i = 0; i < 4; i++) {
        int k = k0 + ty + i * 8;
        tile[ty + i * 8][tx] = Wo[(size_t)k * NCLASS + n0 + tx];
    }
    __syncthreads();
#pragma unroll
    for (int i = 0; i < 4; i++) {
        int n = n0 + ty + i * 8;
        WoT[(size_t)n * NH + k0 + tx] = (bf16)tile[tx][ty + i * 8];
    }
}

__device__ __forceinline__ void flag_add(int* p) {
    __hip_atomic_fetch_add(p, 1, __ATOMIC_RELEASE, __HIP_MEMORY_SCOPE_AGENT);
}
// returns new "dead" state; if dead, skip waiting (degrade to wrong answer, not hang)
__device__ __forceinline__ bool spin8(int* p, bool dead) {
    if (dead) return true;
    int guard = 0;
    while (__hip_atomic_load(p, __ATOMIC_ACQUIRE, __HIP_MEMORY_SCOPE_AGENT) < 8) {
        __builtin_amdgcn_s_sleep(2);
        if (++guard > (4 << 20)) return true;
    }
    return false;
}

__device__ __forceinline__ void zero16(f32x16& v) {
#pragma unroll
    for (int i = 0; i < 16; i++) v[i] = 0.0f;
}

// gather x_t (fp32 C rows -> bf16) into A1 x-region (chunks 0..15, swizzled)
__device__ __forceinline__ void stage_x(const int* __restrict__ X, const float* __restrict__ C,
                                        bf16* A1, int gb, int t, int tid) {
    if (t >= T_SZ) return;
    int r   = tid >> 3;        // 0..63
    int seg = tid & 7;         // 16 floats each
    int idx = X[(gb + r) * T_SZ + t];
    const float4* src = (const float4*)(C + (size_t)idx * EMB + seg * 16);
    float4 v0 = src[0], v1 = src[1], v2 = src[2], v3 = src[3];
    bf16x8 h0, h1v;
    h0[0]=(bf16)v0.x; h0[1]=(bf16)v0.y; h0[2]=(bf16)v0.z; h0[3]=(bf16)v0.w;
    h0[4]=(bf16)v1.x; h0[5]=(bf16)v1.y; h0[6]=(bf16)v1.z; h0[7]=(bf16)v1.w;
    h1v[0]=(bf16)v2.x; h1v[1]=(bf16)v2.y; h1v[2]=(bf16)v2.z; h1v[3]=(bf16)v2.w;
    h1v[4]=(bf16)v3.x; h1v[5]=(bf16)v3.y; h1v[6]=(bf16)v3.z; h1v[7]=(bf16)v3.w;
    int c0 = seg * 2;
    *(bf16x8*)(A1 + r * A1S + chsw(r, c0) * 8)     = h0;
    *(bf16x8*)(A1 + r * A1S + chsw(r, c0 + 1) * 8) = h1v;
}

// pull full h1n (and optionally h2n) for our 64 rows from global into LDS
__device__ __forceinline__ void readback(bf16* A1, bf16* A2,
                                         const bf16* __restrict__ h1p, const bf16* __restrict__ h2p,
                                         int gb, int tid, bool do_h2) {
#pragma unroll
    for (int jj = 0; jj < 4; jj++) {
        int q   = tid + 512 * jj;   // 2048 chunks
        int row = q >> 5;
        int c   = q & 31;
        bf16x8 v = *(const bf16x8*)(h1p + (size_t)(gb + row) * NH + c * 8);
        *(bf16x8*)(A1 + row * A1S + chsw(row, 16 + c) * 8) = v;
        if (do_h2) {
            bf16x8 u = *(const bf16x8*)(h2p + (size_t)(gb + row) * NH + c * 8);
            *(bf16x8*)(A2 + row * A2S + chsw(row, c) * 8) = u;
        }
    }
}

// write acc (2 M-tiles of 32x32 C-layout) into wave-private LDS scratch
__device__ __forceinline__ void acc_to_G(float* Gw, const f32x16& a0, const f32x16& a1, int lane) {
    int col = lane & 31;
    int rh  = 4 * (lane >> 5);
#pragma unroll
    for (int r = 0; r < 16; r++) {
        int row0 = (r & 3) + 8 * (r >> 2) + rh;
        Gw[row0 * GSTR + col]        = a0[r];
        Gw[(row0 + 32) * GSTR + col] = a1[r];
    }
}

// elementwise LSTM cell for 8 nh dims of row `lane`; updates cst, stores h slice
__device__ __forceinline__ void ew_store(const float* Gw, const float* BI, float (&cst)[8],
                                         bf16* __restrict__ hbuf, int gb, int lane, int nhb) {
    bf16x8 hv;
    const float* gr = Gw + lane * GSTR;
#pragma unroll
    for (int j = 0; j < 8; j++) {
        int nh = nhb * 8 + j;
        float pi = gr[0 + j]  + BI[0 * 256 + nh];
        float pf = gr[8 + j]  + BI[1 * 256 + nh];
        float pg = gr[16 + j] + BI[2 * 256 + nh];
        float po = gr[24 + j] + BI[3 * 256 + nh];
        float iv = sigf(pi), fv = sigf(pf), gv = tanhfast(pg), ov = sigf(po);
        float cc = cst[j] * fv + iv * gv;
        cst[j] = cc;
        hv[j] = (bf16)(ov * tanhfast(cc));
    }
    *(bf16x8*)(hbuf + (size_t)(gb + lane) * NH + nhb * 8) = hv;
}

// Persistent weight-stationary 2-layer LSTM.
// Grid 256 = 32 batch-groups(64 rows) x 8 col-groups(32 nh). 512 thr = 8 waves.
// Waves 0-3: layer1 gate-panels in VGPRs; waves 4-7: layer2. h exchange via
// global parity buffers + per-(bg,t) flag counters (release/acquire, agent scope).
__global__ __launch_bounds__(512, 2) void lstm_kernel(
    const int* __restrict__ X, const float* __restrict__ C,
    const bf16* __restrict__ Wt1, const bf16* __restrict__ Wt2,
    const float* __restrict__ b0, const float* __restrict__ b1,
    const float* __restrict__ b2, const float* __restrict__ b3,
    bf16* __restrict__ h1buf, bf16* __restrict__ h2buf,
    int* __restrict__ flags1, int* __restrict__ flags2)
{
    extern __shared__ char smem_raw[];
    bf16*  A1 = (bf16*)smem_raw;                               // 64*392*2 = 50176
    bf16*  A2 = (bf16*)(smem_raw + 50176);                     // 64*264*2 = 33792
    float* G  = (float*)(smem_raw + 50176 + 33792);            // 8*64*33*4 = 67584
    float* BI = (float*)(smem_raw + 50176 + 33792 + 67584);    // 1024*4 = 4096

    const int tid  = threadIdx.x;
    const int lane = tid & 63;
    const int wv   = tid >> 6;
    const int blk  = blockIdx.x;
    const int xcd  = blk & 7;          // assumed round-robin XCD mapping (perf-only)
    const int j5   = blk >> 3;         // 0..31
    const int bg   = xcd * 4 + (j5 & 3);
    const int cg   = j5 >> 2;          // 0..7
    const int gb   = bg * 64;
    int* f1 = flags1 + bg * 512;
    int* f2 = flags2 + bg * 512;

    // biases -> LDS
    {
        const float* bp[4] = { b0, b1, b2, b3 };
        for (int i = tid; i < 1024; i += 512) BI[i] = bp[i >> 8][i & 255];
    }
    // zero h1-region of A1 and all of A2 (h states start at 0)
    {
        bf16x8 z;
#pragma unroll
        for (int i = 0; i < 8; i++) z[i] = (bf16)0.0f;
        for (int q = tid; q < 2048; q += 512) {
            int row = q >> 5, c = q & 31;
            *(bf16x8*)(A1 + row * A1S + chsw(row, 16 + c) * 8) = z;
            *(bf16x8*)(A2 + row * A2S + chsw(row, c) * 8) = z;
        }
    }
    stage_x(X, C, A1, gb, 0, tid);
    __syncthreads();   // B0

    const int hk   = lane >> 5;           // k-half select
    const int r0   = lane & 31;
    const int swz  = ((r0 >> 3) & 3) << 1; // same for row r0 and 32+r0
    bf16* a1p0 = A1 + r0 * A1S;
    bf16* a1p1 = A1 + (32 + r0) * A1S;
    bf16* a2p0 = A2 + r0 * A2S;
    bf16* a2p1 = A2 + (32 + r0) * A2S;
    float* Gw  = G + wv * (64 * GSTR);
    bool dead = false;

    if (wv < 4) {
        // ---------------- layer-1 waves ----------------
        const int nhb = cg * 4 + wv;
        bf16x8 w1[24];
        {
            const bf16* wp = Wt1 + (size_t)(nhb * 32 + r0) * 384 + hk * 8;
#pragma unroll
            for (int kt = 0; kt < 24; kt++) w1[kt] = *(const bf16x8*)(wp + kt * 16);
        }
        float cst[8];
#pragma unroll
        for (int j = 0; j < 8; j++) cst[j] = 0.0f;

        // step 0
        {
            f32x16 ac0, ac1; zero16(ac0); zero16(ac1);
#pragma unroll
            for (int kt = 0; kt < 24; kt++) {
                int off = ((kt * 2 + hk) ^ swz) * 8;
                bf16x8 fa0 = *(const bf16x8*)(a1p0 + off);
                bf16x8 fa1 = *(const bf16x8*)(a1p1 + off);
                ac0 = __builtin_amdgcn_mfma_f32_32x32x16_bf16(fa0, w1[kt], ac0, 0, 0, 0);
                ac1 = __builtin_amdgcn_mfma_f32_32x32x16_bf16(fa1, w1[kt], ac1, 0, 0, 0);
            }
            acc_to_G(Gw, ac0, ac1, lane);
            ew_store(Gw, BI, cst, h1buf /*parity0*/, gb, lane, nhb);
        }
        __threadfence();
        __syncthreads();   // B1
        if (tid == 0) flag_add(f1 + 0);
        dead = spin8(f1 + 0, dead);
        readback(A1, A2, h1buf, h2buf, gb, tid, false);
        stage_x(X, C, A1, gb, 1, tid);
        __syncthreads();   // B2

#pragma unroll 1
        for (int t = 0; t < 256; t++) {
            if (t < 255) {
                f32x16 ac0, ac1; zero16(ac0); zero16(ac1);
#pragma unroll
                for (int kt = 0; kt < 24; kt++) {
                    int off = ((kt * 2 + hk) ^ swz) * 8;
                    bf16x8 fa0 = *(const bf16x8*)(a1p0 + off);
                    bf16x8 fa1 = *(const bf16x8*)(a1p1 + off);
                    ac0 = __builtin_amdgcn_mfma_f32_32x32x16_bf16(fa0, w1[kt], ac0, 0, 0, 0);
                    ac1 = __builtin_amdgcn_mfma_f32_32x32x16_bf16(fa1, w1[kt], ac1, 0, 0, 0);
                }
                acc_to_G(Gw, ac0, ac1, lane);
                ew_store(Gw, BI, cst, h1buf + ((t + 1) & 1) * BH, gb, lane, nhb);
            }
            __threadfence();
            __syncthreads();   // B3
            if (tid == 0 && t < 255) flag_add(f1 + t + 1);
            if (t < 255) {
                dead = spin8(f1 + t + 1, dead);
                dead = spin8(f2 + t, dead);
                readback(A1, A2, h1buf + ((t + 1) & 1) * BH, h2buf + (t & 1) * BH, gb, tid, true);
                stage_x(X, C, A1, gb, t + 2, tid);
            }
            __syncthreads();   // B4
        }
    } else {
        // ---------------- layer-2 waves ----------------
        const int nhb = cg * 4 + (wv - 4);
        bf16x8 w2[32];
        {
            const bf16* wp = Wt2 + (size_t)(nhb * 32 + r0) * 512 + hk * 8;
#pragma unroll
            for (int kt = 0; kt < 32; kt++) w2[kt] = *(const bf16x8*)(wp + kt * 16);
        }
        float cst[8];
#pragma unroll
        for (int j = 0; j < 8; j++) cst[j] = 0.0f;

        __syncthreads();   // B1
        dead = spin8(f1 + 0, dead);
        readback(A1, A2, h1buf, h2buf, gb, tid, false);
        stage_x(X, C, A1, gb, 1, tid);
        __syncthreads();   // B2

#pragma unroll 1
        for (int t = 0; t < 256; t++) {
            {
                f32x16 ac0, ac1; zero16(ac0); zero16(ac1);
#pragma unroll
                for (int kt = 0; kt < 16; kt++) {   // K-half from h1n (A1 chunks 16..47)
                    int off = ((16 + kt * 2 + hk) ^ swz) * 8;
                    bf16x8 fa0 = *(const bf16x8*)(a1p0 + off);
                    bf16x8 fa1 = *(const bf16x8*)(a1p1 + off);
                    ac0 = __builtin_amdgcn_mfma_f32_32x32x16_bf16(fa0, w2[kt], ac0, 0, 0, 0);
                    ac1 = __builtin_amdgcn_mfma_f32_32x32x16_bf16(fa1, w2[kt], ac1, 0, 0, 0);
                }
#pragma unroll
                for (int kt = 16; kt < 32; kt++) {  // K-half from h2 (A2)
                    int off = (((kt - 16) * 2 + hk) ^ swz) * 8;
                    bf16x8 fa0 = *(const bf16x8*)(a2p0 + off);
                    bf16x8 fa1 = *(const bf16x8*)(a2p1 + off);
                    ac0 = __builtin_amdgcn_mfma_f32_32x32x16_bf16(fa0, w2[kt], ac0, 0, 0, 0);
                    ac1 = __builtin_amdgcn_mfma_f32_32x32x16_bf16(fa1, w2[kt], ac1, 0, 0, 0);
                }
                acc_to_G(Gw, ac0, ac1, lane);
                ew_store(Gw, BI, cst, h2buf + (t & 1) * BH, gb, lane, nhb);
            }
            __threadfence();
            __syncthreads();   // B3
            if (tid == 256 && true) flag_add(f2 + t);
            if (t < 255) {
                dead = spin8(f1 + t + 1, dead);
                dead = spin8(f2 + t, dead);
                readback(A1, A2, h1buf + ((t + 1) & 1) * BH, h2buf + (t & 1) * BH, gb, tid, true);
                stage_x(X, C, A1, gb, t + 2, tid);
            }
            __syncthreads();   // B4
        }
    }
}

// out[2048][32000] = h2 @ W_out + b_out
__global__ __launch_bounds__(256, 1) void out_gemm(
    const bf16* __restrict__ h2, const bf16* __restrict__ WoT,
    const float* __restrict__ bout, float* __restrict__ out)
{
    const int tid  = threadIdx.x;
    const int lane = tid & 63;
    const int wv   = tid >> 6;
    const int cl   = lane & 15;
    const int quad = lane >> 4;
    const int nb   = blockIdx.x;
    const int mb   = blockIdx.y;
    const int mbase = mb * 64 + wv * 16;
    const int nbase = nb * 64;

    f32x4 acc[4];
    const f32x4 zf = { 0.0f, 0.0f, 0.0f, 0.0f };
#pragma unroll
    for (int nt = 0; nt < 4; nt++) acc[nt] = zf;

#pragma unroll
    for (int kt = 0; kt < 8; kt++) {
        bf16x8 a = *(const bf16x8*)(h2 + (size_t)(mbase + cl) * NH + kt * 32 + quad * 8);
#pragma unroll
        for (int nt = 0; nt < 4; nt++) {
            bf16x8 b = *(const bf16x8*)(WoT + (size_t)(nbase + nt * 16 + cl) * NH + kt * 32 + quad * 8);
            acc[nt] = __builtin_amdgcn_mfma_f32_16x16x32_bf16(a, b, acc[nt], 0, 0, 0);
        }
    }
#pragma unroll
    for (int nt = 0; nt < 4; nt++) {
        int col = nbase + nt * 16 + cl;
        float bv = bout[col];
#pragma unroll
        for (int r = 0; r < 4; r++) {
            int row = mbase + quad * 4 + r;
            out[(size_t)row * NCLASS + col] = acc[nt][r] + bv;
        }
    }
}

extern "C" void kernel_launch(void* const* d_in, const int* in_sizes, int n_in,
                              void* d_out, int out_size, void* d_ws, size_t ws_size,
                              hipStream_t stream) {
    const int*   X  = (const int*)d_in[0];
    const float* C  = (const float*)d_in[1];
    GatePtrs gp;
    for (int g = 0; g < 4; g++) {
        int base = 2 + 5 * g;
        gp.U1[g] = (const float*)d_in[base + 0];
        gp.V1[g] = (const float*)d_in[base + 1];
        gp.U2[g] = (const float*)d_in[base + 2];
        gp.V2[g] = (const float*)d_in[base + 3];
    }
    const float* bi   = (const float*)d_in[6];
    const float* bf_  = (const float*)d_in[11];
    const float* bc   = (const float*)d_in[16];
    const float* bo   = (const float*)d_in[21];
    const float* Wo   = (const float*)d_in[22];
    const float* bout = (const float*)d_in[23];
    float* out = (float*)d_out;

    char* ws = (char*)d_ws;
    const size_t OFF_WT2 = 786432;
    const size_t OFF_WOT = 1835008;
    const size_t OFF_H1  = 18219008;
    const size_t OFF_H2  = 20316160;
    const size_t OFF_FLG = 22413312;
    bf16* Wt1 = (bf16*)(ws);
    bf16* Wt2 = (bf16*)(ws + OFF_WT2);
    bf16* WoT = (bf16*)(ws + OFF_WOT);
    bf16* h1b = (bf16*)(ws + OFF_H1);
    bf16* h2b = (bf16*)(ws + OFF_H2);
    int*  fl1 = (int*)(ws + OFF_FLG);
    int*  fl2 = (int*)(ws + OFF_FLG + 65536);

    hipMemsetAsync(ws + OFF_FLG, 0, 131072, stream);
    prep_w1<<<dim3(1024), dim3(384), 0, stream>>>(gp, Wt1);
    prep_w2<<<dim3(1024), dim3(512), 0, stream>>>(gp, Wt2);
    prep_wo<<<dim3(1000, 8), dim3(256), 0, stream>>>(Wo, WoT);

    hipFuncSetAttribute((const void*)lstm_kernel,
                        hipFuncAttributeMaxDynamicSharedMemorySize, 155648);
    lstm_kernel<<<dim3(256), dim3(512), 155648, stream>>>(
        X, C, Wt1, Wt2, bi, bf_, bc, bo, h1b, h2b, fl1, fl2);

    out_gemm<<<dim3(500, 32), dim3(256), 0, stream>>>(h2b + BH, WoT, bout, out);
}